// Round 3
// baseline (644.341 us; speedup 1.0000x reference)
//
#include <hip/hip_runtime.h>
#include <hip/hip_bf16.h>
#include <cstdint>
#include <cstddef>

// Problem constants (from reference setup_inputs): B=8, S=4096, IN=OUT=2048
// Harness canonicalizes fp16 tensors to FLOAT32 buffers on both input and
// output ("else float*"), but the reference ARITHMETIC is fp16 — we replicate
// fp16 (RNE) semantics with _Float16 ops on fp16-representable fp32 values.
#define M_TOT 32768   // B*S
#define N_OUT 2048
#define K_IN  2048

typedef int v4i __attribute__((ext_vector_type(4)));

// async global->LDS, 16B per lane; lds base must be wave-uniform
__device__ __forceinline__ void gload16(const int8_t* g, int8_t* l) {
  __builtin_amdgcn_global_load_lds(
      (const __attribute__((address_space(1))) void*)g,
      (__attribute__((address_space(3))) void*)l, 16, 0, 0);
}

// ---------------------------------------------------------------------------
// Kernel 1/2: per-row smooth + quantize, exact fp16 reference semantics.
//   mode 0 (activations): xs = fp16(x / scales)   (fp16 division)
//   mode 1 (weights):     xs = fp16(w * scales)
//   rmax[row] = fp16(max|xs| / 127);  q = trunc(fp16(xs / rmax)) as int8
// One block per row (K_IN = 2048 = 256 threads * 8 elems).
// ---------------------------------------------------------------------------
__global__ __launch_bounds__(256) void quant_rows_kernel(
    const float* __restrict__ in,      // fp32 (fp16-representable) [rows][K_IN]
    const float* __restrict__ scales,  // fp32 (fp16-representable) [K_IN]
    int8_t* __restrict__ q, float* __restrict__ rmax, int mul_mode)
{
  const int row = blockIdx.x;
  const int tid = threadIdx.x;
  const size_t base = (size_t)row * K_IN + tid * 8;
  const float4 xv0 = *(const float4*)(in + base);
  const float4 xv1 = *(const float4*)(in + base + 4);
  const float4 sv0 = *(const float4*)(scales + tid * 8);
  const float4 sv1 = *(const float4*)(scales + tid * 8 + 4);
  const float xf[8] = {xv0.x, xv0.y, xv0.z, xv0.w, xv1.x, xv1.y, xv1.z, xv1.w};
  const float sf[8] = {sv0.x, sv0.y, sv0.z, sv0.w, sv1.x, sv1.y, sv1.z, sv1.w};
  _Float16 xs[8];
  float amax = 0.f;
#pragma unroll
  for (int i = 0; i < 8; ++i) {
    const _Float16 hx = (_Float16)xf[i];
    const _Float16 hs = (_Float16)sf[i];
    xs[i] = mul_mode ? (_Float16)(hx * hs) : (_Float16)(hx / hs);  // fp16 RNE
    amax = fmaxf(amax, fabsf((float)xs[i]));
  }
  // wave64 reduce then cross-wave via LDS
#pragma unroll
  for (int off = 32; off; off >>= 1) amax = fmaxf(amax, __shfl_down(amax, off));
  __shared__ float red[4];
  const int wid = tid >> 6, lane = tid & 63;
  if (lane == 0) red[wid] = amax;
  __syncthreads();
  amax = fmaxf(fmaxf(red[0], red[1]), fmaxf(red[2], red[3]));
  _Float16 hqm = (_Float16)amax / (_Float16)127.0f;   // fp16(max/QMAX)
  if (tid == 0) rmax[row] = (float)hqm;
  if (hqm == (_Float16)0.f) hqm = (_Float16)1.0f;     // defensive 0/0 guard
  int8_t qb[8];
#pragma unroll
  for (int i = 0; i < 8; ++i) {
    const float qf = (float)(_Float16)(xs[i] / hqm);  // fp16 division result
    qb[i] = (int8_t)(int)qf;                          // truncate toward zero
  }
  unsigned long long pk;
  __builtin_memcpy(&pk, qb, 8);
  *(unsigned long long*)(q + (size_t)row * K_IN + tid * 8) = pk;
}

// ---------------------------------------------------------------------------
// Kernel 3: int8 GEMM, C[m,n] = sum_k Aq[m,k]*Bq[n,k] (both K-major), fused
// dequant epilogue: out = fp32(fp16(fp32(acc) * fp16(xm*wm)_f32) + bias).
// m97-ladder structure: 128x128 tile, 4 waves (2x2), BK=64 int8,
// global_load_lds width 16, mfma_i32_16x16x64_i8 4x4 per wave.
// ---------------------------------------------------------------------------
__global__ __launch_bounds__(256) void gemm_i8_kernel(
    const int8_t* __restrict__ Aq, const int8_t* __restrict__ Bq,
    const float* __restrict__ Am, const float* __restrict__ Bm,
    const float* __restrict__ bias, float* __restrict__ out)
{
  __shared__ int8_t sA[128 * 64];
  __shared__ int8_t sB[128 * 64];
  const int tid = threadIdx.x;
  const int wid = tid >> 6, lane = tid & 63;
  const int wm = wid >> 1, wn = wid & 1;
  const long bm = (long)blockIdx.x * 128;
  const long bn = (long)blockIdx.y * 128;

  // staging: wave wid stages rows [wid*32, wid*32+32) of both tiles,
  // two 1024B wave-loads (16 rows x 64B each); LDS layout [128][64] row-major.
  // lane -> (row lane>>2, col 16*(lane&3)) -> LDS offset lane*16 (contiguous).
  const int srow = wid * 32 + (lane >> 2);
  const int scol = (lane & 3) * 16;
  const int8_t* ga = Aq + (bm + srow) * K_IN + scol;
  const int8_t* gb = Bq + (bn + srow) * K_IN + scol;
  int8_t* lA = sA + wid * 2048;
  int8_t* lB = sB + wid * 2048;

  // fragment reads: A[m=lane&15][k=quad*16+j], same for B (K-major)
  const int fr = lane & 15, fq = lane >> 4;
  const int8_t* ra = sA + (wm * 64 + fr) * 64 + fq * 16;
  const int8_t* rb = sB + (wn * 64 + fr) * 64 + fq * 16;

  v4i acc[4][4] = {};

  for (int kt = 0; kt < K_IN; kt += 64) {
    __syncthreads();
    gload16(ga + kt,             lA);
    gload16(ga + 16 * K_IN + kt, lA + 1024);
    gload16(gb + kt,             lB);
    gload16(gb + 16 * K_IN + kt, lB + 1024);
    __syncthreads();
    v4i a[4], b[4];
#pragma unroll
    for (int i = 0; i < 4; ++i) a[i] = *(const v4i*)(ra + i * 16 * 64);
#pragma unroll
    for (int i = 0; i < 4; ++i) b[i] = *(const v4i*)(rb + i * 16 * 64);
#pragma unroll
    for (int mi = 0; mi < 4; ++mi)
#pragma unroll
      for (int ni = 0; ni < 4; ++ni)
        acc[mi][ni] = __builtin_amdgcn_mfma_i32_16x16x64_i8(a[mi], b[ni], acc[mi][ni], 0, 0, 0);
  }

  // epilogue; C/D layout: col = lane&15, row = (lane>>4)*4 + reg  [m89-verified]
  const long cm0 = bm + wm * 64;
  const int  cn0 = (int)bn + wn * 64;
  float amv[4][4];
#pragma unroll
  for (int mi = 0; mi < 4; ++mi)
#pragma unroll
    for (int r = 0; r < 4; ++r)
      amv[mi][r] = Am[cm0 + mi * 16 + fq * 4 + r];
#pragma unroll
  for (int ni = 0; ni < 4; ++ni) {
    const int col = cn0 + ni * 16 + fr;
    const float wmv = Bm[col];
    const _Float16 bsv = (_Float16)bias[col];
#pragma unroll
    for (int mi = 0; mi < 4; ++mi) {
#pragma unroll
      for (int r = 0; r < 4; ++r) {
        const long row = cm0 + mi * 16 + fq * 4 + r;
        // mx = fp16(x_max * w_max), promoted to fp32
        const float mx = (float)(_Float16)((_Float16)amv[mi][r] * (_Float16)wmv);
        // res = fp16(res_q_f32 * mx); res = res + bias (fp16 add)
        const _Float16 resh = (_Float16)((float)acc[mi][ni][r] * mx);
        out[row * N_OUT + col] = (float)(_Float16)(resh + bsv);
      }
    }
  }
}

extern "C" void kernel_launch(void* const* d_in, const int* in_sizes, int n_in,
                              void* d_out, int out_size, void* d_ws, size_t ws_size,
                              hipStream_t stream) {
  const float* x      = (const float*)d_in[0];  // [8,4096,2048] fp32 (fp16 values)
  const float* ori_w  = (const float*)d_in[1];  // [2048,2048]
  const float* scales = (const float*)d_in[2];  // [2048]
  const float* bias   = (const float*)d_in[3];  // [2048]
  float* out = (float*)d_out;                   // [8,4096,2048] fp32

  // workspace layout: xq (64MB) | wq (4MB) | xm (128KB fp32) | wm (8KB fp32)
  int8_t* xq = (int8_t*)d_ws;
  int8_t* wq = xq + (size_t)M_TOT * K_IN;
  float*  xm = (float*)(wq + (size_t)N_OUT * K_IN);
  float*  wmx = xm + M_TOT;

  quant_rows_kernel<<<M_TOT, 256, 0, stream>>>(x, scales, xq, xm, 0);
  quant_rows_kernel<<<N_OUT, 256, 0, stream>>>(ori_w, scales, wq, wmx, 1);

  dim3 grid(M_TOT / 128, N_OUT / 128);
  gemm_i8_kernel<<<grid, 256, 0, stream>>>(xq, wq, xm, wmx, bias, out);
}

// Round 4
// 638.318 us; speedup vs baseline: 1.0094x; 1.0094x over previous
//
#include <hip/hip_runtime.h>
#include <hip/hip_bf16.h>
#include <cstdint>
#include <cstddef>

// Problem constants (from reference setup_inputs): B=8, S=4096, IN=OUT=2048
// Harness canonicalizes fp16 tensors to FLOAT32 buffers on both input and
// output; reference ARITHMETIC is fp16 — replicated with _Float16 ops.
#define M_TOT 32768   // B*S
#define N_OUT 2048
#define K_IN  2048

typedef int v4i __attribute__((ext_vector_type(4)));

// async global->LDS, 16B per lane; lds base must be wave-uniform
__device__ __forceinline__ void gload16(const int8_t* g, int8_t* l) {
  __builtin_amdgcn_global_load_lds(
      (const __attribute__((address_space(1))) void*)g,
      (__attribute__((address_space(3))) void*)l, 16, 0, 0);
}

// ---------------------------------------------------------------------------
// Kernel 1/2: per-row smooth + quantize, exact fp16 reference semantics.
//   mode 0 (activations): xs = fp16(x / scales)   (fp16 division)
//   mode 1 (weights):     xs = fp16(w * scales)
//   rmax[row] = fp16(max|xs| / 127);  q = trunc(fp16(xs / rmax)) as int8
// One block per row (K_IN = 2048 = 256 threads * 8 elems).
// ---------------------------------------------------------------------------
__global__ __launch_bounds__(256) void quant_rows_kernel(
    const float* __restrict__ in,      // fp32 (fp16-representable) [rows][K_IN]
    const float* __restrict__ scales,  // fp32 (fp16-representable) [K_IN]
    int8_t* __restrict__ q, float* __restrict__ rmax, int mul_mode)
{
  const int row = blockIdx.x;
  const int tid = threadIdx.x;
  const size_t base = (size_t)row * K_IN + tid * 8;
  const float4 xv0 = *(const float4*)(in + base);
  const float4 xv1 = *(const float4*)(in + base + 4);
  const float4 sv0 = *(const float4*)(scales + tid * 8);
  const float4 sv1 = *(const float4*)(scales + tid * 8 + 4);
  const float xf[8] = {xv0.x, xv0.y, xv0.z, xv0.w, xv1.x, xv1.y, xv1.z, xv1.w};
  const float sf[8] = {sv0.x, sv0.y, sv0.z, sv0.w, sv1.x, sv1.y, sv1.z, sv1.w};
  _Float16 xs[8];
  float amax = 0.f;
#pragma unroll
  for (int i = 0; i < 8; ++i) {
    const _Float16 hx = (_Float16)xf[i];
    const _Float16 hs = (_Float16)sf[i];
    xs[i] = mul_mode ? (_Float16)(hx * hs) : (_Float16)(hx / hs);  // fp16 RNE
    amax = fmaxf(amax, fabsf((float)xs[i]));
  }
  // wave64 reduce then cross-wave via LDS
#pragma unroll
  for (int off = 32; off; off >>= 1) amax = fmaxf(amax, __shfl_down(amax, off));
  __shared__ float red[4];
  const int wid = tid >> 6, lane = tid & 63;
  if (lane == 0) red[wid] = amax;
  __syncthreads();
  amax = fmaxf(fmaxf(red[0], red[1]), fmaxf(red[2], red[3]));
  _Float16 hqm = (_Float16)amax / (_Float16)127.0f;   // fp16(max/QMAX)
  if (tid == 0) rmax[row] = (float)hqm;
  if (hqm == (_Float16)0.f) hqm = (_Float16)1.0f;     // defensive 0/0 guard
  int8_t qb[8];
#pragma unroll
  for (int i = 0; i < 8; ++i) {
    const float qf = (float)(_Float16)(xs[i] / hqm);  // fp16 division result
    qb[i] = (int8_t)(int)qf;                          // truncate toward zero
  }
  unsigned long long pk;
  __builtin_memcpy(&pk, qb, 8);
  *(unsigned long long*)(q + (size_t)row * K_IN + tid * 8) = pk;
}

// ---------------------------------------------------------------------------
// Kernel 3: int8 GEMM, C[m,n] = sum_k Aq[m,k]*Bq[n,k] (both K-major), fused
// dequant epilogue: out = fp32(fp16(fp32(acc) * fp16(xm*wm)_f32) + bias).
// m97-ladder structure: 128x128 tile, 4 waves (2x2), BK=64 int8,
// global_load_lds width 16, mfma_i32_16x16x64_i8 4x4 per wave.
//
// LDS bank-conflict fix (R4): XOR chunk swizzle. Row r's 16B k-chunk c is
// stored at position p = c ^ ((r>>1)&3). global_load_lds dest must stay
// base+lane*16, so the permutation is applied to the per-lane GLOBAL source
// address at staging, and to the ds_read offset at fragment-read. p is
// invariant under r += 16 (both staging's second load and the 4 fragment
// rows), so one swizzle term serves all. 16-lane read phase now covers all
// 8 bank-groups (was 2 -> 4-way serialization, 1.7e7 conflict cycles).
// ---------------------------------------------------------------------------
__global__ __launch_bounds__(256) void gemm_i8_kernel(
    const int8_t* __restrict__ Aq, const int8_t* __restrict__ Bq,
    const float* __restrict__ Am, const float* __restrict__ Bm,
    const float* __restrict__ bias, float* __restrict__ out)
{
  __shared__ int8_t sA[128 * 64];
  __shared__ int8_t sB[128 * 64];
  const int tid = threadIdx.x;
  const int wid = tid >> 6, lane = tid & 63;
  const int wm = wid >> 1, wn = wid & 1;
  // grid: x = N-tile (fast), y = M-tile -> 16 consecutive blocks share one
  // A-tile (L2 reuse); whole B (4MB) stays hot.
  const long bm = (long)blockIdx.y * 128;
  const long bn = (long)blockIdx.x * 128;

  // staging: wave wid stages rows [wid*32, wid*32+32) of both tiles.
  // lane -> LDS (row lane>>2, pos lane&3); source chunk c = pos ^ ((row>>1)&3),
  // where ((srow)>>1)&3 == (lane>>3)&3  (wid*16 ≡ 0 mod 4).
  const int srow = wid * 32 + (lane >> 2);
  const int scol = (((lane & 3) ^ ((lane >> 3) & 3))) * 16;
  const int8_t* ga = Aq + (bm + srow) * K_IN + scol;
  const int8_t* gb = Bq + (bn + srow) * K_IN + scol;
  int8_t* lA = sA + wid * 2048;
  int8_t* lB = sB + wid * 2048;

  // fragment reads: A[m=lane&15][k=quad*16+j]; chunk fq of row fr sits at
  // swizzled pos fq ^ ((fr>>1)&3). Same for B (K-major).
  const int fr = lane & 15, fq = lane >> 4;
  const int fp = (fq ^ ((fr >> 1) & 3)) * 16;
  const int8_t* ra = sA + (wm * 64 + fr) * 64 + fp;
  const int8_t* rb = sB + (wn * 64 + fr) * 64 + fp;

  v4i acc[4][4] = {};

  for (int kt = 0; kt < K_IN; kt += 64) {
    __syncthreads();
    gload16(ga + kt,             lA);
    gload16(ga + 16 * K_IN + kt, lA + 1024);
    gload16(gb + kt,             lB);
    gload16(gb + 16 * K_IN + kt, lB + 1024);
    __syncthreads();
    v4i a[4], b[4];
#pragma unroll
    for (int i = 0; i < 4; ++i) a[i] = *(const v4i*)(ra + i * 16 * 64);
#pragma unroll
    for (int i = 0; i < 4; ++i) b[i] = *(const v4i*)(rb + i * 16 * 64);
#pragma unroll
    for (int mi = 0; mi < 4; ++mi)
#pragma unroll
      for (int ni = 0; ni < 4; ++ni)
        acc[mi][ni] = __builtin_amdgcn_mfma_i32_16x16x64_i8(a[mi], b[ni], acc[mi][ni], 0, 0, 0);
  }

  // epilogue; C/D layout: col = lane&15, row = (lane>>4)*4 + reg  [m89-verified]
  const long cm0 = bm + wm * 64;
  const int  cn0 = (int)bn + wn * 64;
  float amv[4][4];
#pragma unroll
  for (int mi = 0; mi < 4; ++mi)
#pragma unroll
    for (int r = 0; r < 4; ++r)
      amv[mi][r] = Am[cm0 + mi * 16 + fq * 4 + r];
#pragma unroll
  for (int ni = 0; ni < 4; ++ni) {
    const int col = cn0 + ni * 16 + fr;
    const float wmv = Bm[col];
    const _Float16 bsv = (_Float16)bias[col];
#pragma unroll
    for (int mi = 0; mi < 4; ++mi) {
#pragma unroll
      for (int r = 0; r < 4; ++r) {
        const long row = cm0 + mi * 16 + fq * 4 + r;
        // mx = fp16(x_max * w_max), promoted to fp32
        const float mx = (float)(_Float16)((_Float16)amv[mi][r] * (_Float16)wmv);
        // res = fp16(res_q_f32 * mx); res = res + bias (fp16 add)
        const _Float16 resh = (_Float16)((float)acc[mi][ni][r] * mx);
        out[row * N_OUT + col] = (float)(_Float16)(resh + bsv);
      }
    }
  }
}

extern "C" void kernel_launch(void* const* d_in, const int* in_sizes, int n_in,
                              void* d_out, int out_size, void* d_ws, size_t ws_size,
                              hipStream_t stream) {
  const float* x      = (const float*)d_in[0];  // [8,4096,2048] fp32 (fp16 values)
  const float* ori_w  = (const float*)d_in[1];  // [2048,2048]
  const float* scales = (const float*)d_in[2];  // [2048]
  const float* bias   = (const float*)d_in[3];  // [2048]
  float* out = (float*)d_out;                   // [8,4096,2048] fp32

  // workspace layout: xq (64MB) | wq (4MB) | xm (128KB fp32) | wm (8KB fp32)
  int8_t* xq = (int8_t*)d_ws;
  int8_t* wq = xq + (size_t)M_TOT * K_IN;
  float*  xm = (float*)(wq + (size_t)N_OUT * K_IN);
  float*  wmx = xm + M_TOT;

  quant_rows_kernel<<<M_TOT, 256, 0, stream>>>(x, scales, xq, xm, 0);
  quant_rows_kernel<<<N_OUT, 256, 0, stream>>>(ori_w, scales, wq, wmx, 1);

  dim3 grid(N_OUT / 128, M_TOT / 128);   // N fast, M slow (A-tile L2 reuse)
  gemm_i8_kernel<<<grid, 256, 0, stream>>>(xq, wq, xm, wmx, bias, out);
}